// Round 16
// baseline (567.458 us; speedup 1.0000x reference)
//
#include <hip/hip_runtime.h>
#include <math.h>

#define NPTS 4096
#define NB 2
#define K_TOTAL 12
#define BLOCK 256
#define TILE 128
#define NT (NPTS / TILE)   // 32 tile-blocks per dimension

// ws layout (floats / 4B words), double-buffered by step parity:
//  [0..24)     sched: 12 x {eps, w}
//  [32..544)   ML: 2 par x 8 pb x 32 tiles  (tile-local max of h)
//  [576..)     P:  2 par x 8 pb x 4096
//  [66112..)   RED: 64 doubles (block partials of final reduce)
//  [66240..)   PART: 2 par x 8 pb x 32 slots x 4096 (exactly-once writes)
#define SCHED_OFF 0
#define ML_OFF 32
#define P_OFF 576
#define POT_SZ (4 * NB * NPTS)          // 32768
#define RED_OFF (P_OFF + 2 * POT_SZ)    // 66112 (byte offset %8==0: ok for double)
#define PART_OFF (RED_OFF + 128)        // 66240
#define PART_SZ (4 * NB * NT * NPTS)    // 1048576 floats per parity

#if __has_builtin(__builtin_amdgcn_exp2f)
#define EXP2F __builtin_amdgcn_exp2f
#else
#define EXP2F exp2f
#endif
#if __has_builtin(__builtin_amdgcn_logf)
#define LOG2F __builtin_amdgcn_logf
#else
#define LOG2F log2f
#endif
#if __has_builtin(__builtin_amdgcn_sqrtf)
#define FSQRTF __builtin_amdgcn_sqrtf
#else
#define FSQRTF sqrtf
#endif

#define BASE_LOGW -8.31776616671934f  // -log(4096), N==M
#define LOG2E 1.4426950408889634f
#define LN2 0.69314718055994531f

typedef float v2f __attribute__((ext_vector_type(2)));

// ---------------------------------------------------------------------------
// Kernel A (grid=64 x 256): block 0 computes diameter (f32, matching numpy) +
// eps schedule (f64, matching np.arange/np.exp); blocks 1..63 zero both P
// parity buffers.
// ---------------------------------------------------------------------------
__global__ __launch_bounds__(256) void k_init(
    const float2* __restrict__ x, const float2* __restrict__ y, float* ws)
{
  const int tid = threadIdx.x;
  const int bid = blockIdx.x;

  if (bid > 0) {
    for (int i = (bid - 1) * 256 + tid; i < 2 * POT_SZ; i += 63 * 256)
      ws[P_OFF + i] = 0.0f;
    return;
  }

  float mnx = 1e30f, mny = 1e30f, mxx = -1e30f, mxy = -1e30f;
  for (int i = tid; i < NB * NPTS; i += 256) {
    float2 p = x[i];
    mnx = fminf(mnx, p.x); mxx = fmaxf(mxx, p.x);
    mny = fminf(mny, p.y); mxy = fmaxf(mxy, p.y);
    float2 q = y[i];
    mnx = fminf(mnx, q.x); mxx = fmaxf(mxx, q.x);
    mny = fminf(mny, q.y); mxy = fmaxf(mxy, q.y);
  }
  for (int o = 32; o; o >>= 1) {
    mnx = fminf(mnx, __shfl_xor(mnx, o, 64));
    mxx = fmaxf(mxx, __shfl_xor(mxx, o, 64));
    mny = fminf(mny, __shfl_xor(mny, o, 64));
    mxy = fmaxf(mxy, __shfl_xor(mxy, o, 64));
  }
  __shared__ float r[4][4];
  const int wave = tid >> 6, lane = tid & 63;
  if (lane == 0) { r[0][wave] = mnx; r[1][wave] = mxx; r[2][wave] = mny; r[3][wave] = mxy; }
  __syncthreads();
  if (tid == 0) {
    mnx = fminf(fminf(r[0][0], r[0][1]), fminf(r[0][2], r[0][3]));
    mxx = fmaxf(fmaxf(r[1][0], r[1][1]), fmaxf(r[1][2], r[1][3]));
    mny = fminf(fminf(r[2][0], r[2][1]), fminf(r[2][2], r[2][3]));
    mxy = fmaxf(fmaxf(r[3][0], r[3][1]), fmaxf(r[3][2], r[3][3]));
    float rx = mxx - mnx, ry = mxy - mny;
    float dia = sqrtf(rx * rx + ry * ry);

    double a = log((double)dia);
    double stop = log(0.05);
    double stp = log(0.5);
    int cnt = (int)ceil((stop - a) / stp);  // data: cnt == 8
    if (cnt < 0) cnt = 0;
    if (cnt > K_TOTAL - 4) cnt = K_TOTAL - 4;

    float* sch = ws + SCHED_OFF;
    sch[0] = dia; sch[1] = 0.0f;   // init: direct assign at eps=diameter
    sch[2] = dia; sch[3] = 0.5f;   // loop over eps_list, w=0.5
    for (int k = 0; k < cnt; k++) {
      sch[2 * (2 + k)] = (float)exp(a + (double)k * stp);
      sch[2 * (2 + k) + 1] = 0.5f;
    }
    sch[2 * (2 + cnt)] = 0.05f; sch[2 * (2 + cnt) + 1] = 0.5f;
    for (int s = 3 + cnt; s < K_TOTAL - 1; s++) { sch[2 * s] = 0.05f; sch[2 * s + 1] = 1.0f; }
    sch[2 * (K_TOTAL - 1)] = 0.05f; sch[2 * (K_TOTAL - 1) + 1] = 0.0f;  // final extrapolation
  }
}

// ---------------------------------------------------------------------------
// Kernel B: 256-thread K-tile sweep with fused combine (round 9 structure,
// measured 412.5-413.0 us total across 3 runs).
// ONLY change this round: launch_bounds (256,4) -> (256,6). The 2nd arg is a
// register-allocator MINIMUM (not an occupancy cap); natural VGPR is in
// (64,128] (r10: <=128 null; r13: forced-64 spilled). Cap 85 targets 6
// blocks/CU co-resident vs ~4-5. Live set ~72 VGPRs -> 13 of headroom.
// Pre-committed: spill signature (WRITE>20MB) or null -> revert, converged.
// ---------------------------------------------------------------------------
__global__ __launch_bounds__(BLOCK, 6) void k_tiles(
    const float2* __restrict__ xpts, const float2* __restrict__ ypts,
    float* __restrict__ ws, int stepi)
{
  __shared__ float rXs[TILE], rYs[TILE], rVs[TILE];
  __shared__ float cXs[144], cYs[144], cVs[144];  // padded: idx + idx/8
  __shared__ float tPart[16][129];                // reused for rows then cols
  __shared__ float sfb[2][32];                    // combine scale factors per side
  __shared__ float smx[2];                        // Mmax per side
  __shared__ float wmax[4];                       // per-wave h-max scratch

  const int tid = threadIdx.x;
  const int id = blockIdx.x;

  const float2* rowp; const float2* colp;
  int ti, tj, pbr, pbc;
  bool dual;

  if (id < NB * NT * NT) {
    const int b = id >> 10;
    const int t = id & (NT * NT - 1);
    ti = t >> 5; tj = t & (NT - 1);
    rowp = xpts + b * NPTS; colp = ypts + b * NPTS;
    pbr = 0 * NB + b; pbc = 1 * NB + b;   // rows: f_ba side; cols: g_ab side
    dual = true;
  } else {
    const int id2 = id - NB * NT * NT;    // [0, 2112)
    const int mat = id2 / 1056;           // 0: C_xx, 1: C_yy
    const int rem = id2 - mat * 1056;
    const int b = rem / 528;
    const int k = rem - b * 528;          // triangle index, ti <= tj
    int t0 = (int)((65.0f - FSQRTF((float)(4225 - 8 * k))) * 0.5f);
    while (t0 * (65 - t0) / 2 > k) t0--;
    while ((t0 + 1) * (64 - t0) / 2 <= k) t0++;
    ti = t0; tj = t0 + (k - t0 * (65 - t0) / 2);
    const float2* pts = mat ? ypts : xpts;
    rowp = pts + b * NPTS; colp = rowp;
    pbr = (2 + mat) * NB + b; pbc = pbr;
    dual = (ti != tj);                    // diagonal tile: row sums only
  }

  const float eps = ws[SCHED_OFF + 2 * stepi];
  const float sc = LOG2E / eps;       // exp2(-sqrt(d2_scaled)) = e^{-d/eps}
  const float inv_eps = 1.0f / eps;   // h = logw + P/eps
  const int ppar = (stepi - 1) & 1;   // parity of prev step's parts/ML; P_new written here
  const int cpar = stepi & 1;         // parity of this step's parts/ML; P_old read here

  // ---- Phase A: wave 0 builds combine scale factors from prev-step ML ----
  if (stepi > 0 && tid < 64) {
    const int c = tid & 31, side = tid >> 5;
    const int pb_own = side ? pbc : pbr;
    const int spb = (pb_own < 4) ? (pb_own ^ 2) : pb_own;  // V-pot partner
    float ml = ws[ML_OFF + ppar * 256 + spb * NT + c];
    float mm = ml;
    mm = fmaxf(mm, __shfl_xor(mm, 1, 64));
    mm = fmaxf(mm, __shfl_xor(mm, 2, 64));
    mm = fmaxf(mm, __shfl_xor(mm, 4, 64));
    mm = fmaxf(mm, __shfl_xor(mm, 8, 64));
    mm = fmaxf(mm, __shfl_xor(mm, 16, 64));
    sfb[side][c] = EXP2F((ml - mm) * LOG2E);
    if (c == 0) smx[side] = mm;
  }
  __syncthreads();

  // ---- Phase B: per-point combine (step t-1) + h ----
  const int side = tid >> 7, kk0 = tid & 127;
  const int pb_own = side ? pbc : pbr;
  const int tile_own = side ? tj : ti;
  const int r = tile_own * TILE + kk0;
  float2 pt = (side ? colp : rowp)[r];

  float h;
  if (stepi == 0) {
    h = BASE_LOGW;                     // P = 0
  } else {
    const float eps_p = ws[SCHED_OFF + 2 * (stepi - 1)];
    const float w_p = ws[SCHED_OFF + 2 * (stepi - 1) + 1];
    const float* pprev = ws + PART_OFF + ppar * PART_SZ + (pb_own * NT) * NPTS + r;
    float s = 0.0f;
#pragma unroll
    for (int c = 0; c < NT; c++) s += pprev[c * NPTS] * sfb[side][c];
    s = fmaxf(s, 1e-37f);
    float ft = -eps_p * fmaf(LN2, LOG2F(s), smx[side]);
    float po = ws[P_OFF + cpar * POT_SZ + pb_own * NPTS + r];
    float pn = (w_p >= 1.0f) ? po : fmaf(w_p, po, (1.0f - w_p) * ft);
    ws[P_OFF + ppar * POT_SZ + pb_own * NPTS + r] = pn;  // identical-value race OK
    h = fmaf(pn, inv_eps, BASE_LOGW);
  }

  // ---- per-side Mloc = max h over the side's 128 points ----
  float hm = h;
  for (int o = 32; o; o >>= 1) hm = fmaxf(hm, __shfl_xor(hm, o, 64));
  if ((tid & 63) == 0) wmax[tid >> 6] = hm;
  __syncthreads();
  const float Mloc = fmaxf(wmax[2 * side], wmax[2 * side + 1]);

  // ---- Phase C: stage scaled coords + V; record ML ----
  if (side == 0) {
    rXs[kk0] = pt.x * sc; rYs[kk0] = pt.y * sc;
    rVs[kk0] = EXP2F((h - Mloc) * LOG2E);
  } else {
    const int kk = kk0 + (kk0 >> 3);  // pad to break 4-way preload conflict
    cXs[kk] = pt.x * sc; cYs[kk] = pt.y * sc;
    cVs[kk] = EXP2F((h - Mloc) * LOG2E);
  }
  if (kk0 == 0) ws[ML_OFF + cpar * 256 + pb_own * NT + tile_own] = Mloc;
  __syncthreads();

  // ---- inner loop: packed f32, 8 rows x 8 cols per thread ----
  const int tx = tid & 15, ty = tid >> 4;
  float rx[8], ry[8], rv[8];
  v2f cx2[4], cy2[4], cv2[4], racc2[8], cacc2[4];
#pragma unroll
  for (int q = 0; q < 8; q++) {
    rx[q] = rXs[ty * 8 + q]; ry[q] = rYs[ty * 8 + q]; rv[q] = rVs[ty * 8 + q];
    racc2[q] = (v2f){0.0f, 0.0f};
  }
#pragma unroll
  for (int j = 0; j < 4; j++) {
    const int ci = tx * 9 + 2 * j;
    cx2[j] = (v2f){cXs[ci], cXs[ci + 1]};
    cy2[j] = (v2f){cYs[ci], cYs[ci + 1]};
    cv2[j] = (v2f){cVs[ci], cVs[ci + 1]};
    cacc2[j] = (v2f){0.0f, 0.0f};
  }

#pragma unroll
  for (int q = 0; q < 8; q++) {
    const v2f rxq = (v2f){rx[q], rx[q]};
    const v2f ryq = (v2f){ry[q], ry[q]};
    const v2f rvq = (v2f){rv[q], rv[q]};
#pragma unroll
    for (int j = 0; j < 4; j++) {
      v2f dx = rxq - cx2[j];
      v2f dy = ryq - cy2[j];
      v2f d2 = dx * dx + dy * dy;
      float t0 = FSQRTF(d2.x), t1 = FSQRTF(d2.y);
      v2f K = (v2f){EXP2F(-t0), EXP2F(-t1)};
      racc2[q] += K * cv2[j];
      cacc2[j] += K * rvq;
    }
  }

  float* part = ws + PART_OFF + cpar * PART_SZ;

  // rows: transpose via LDS, 128-lane sum, store to slot tj
#pragma unroll
  for (int q = 0; q < 8; q++) tPart[tx][ty * 8 + q] = racc2[q].x + racc2[q].y;
  __syncthreads();
  if (tid < TILE) {
    float s = 0.0f;
#pragma unroll
    for (int t = 0; t < 16; t++) s += tPart[t][tid];
    part[(pbr * NT + tj) * NPTS + ti * TILE + tid] = s;
  }
  __syncthreads();

  // cols: same buffer, slot ti
#pragma unroll
  for (int j = 0; j < 4; j++) {
    tPart[ty][tx * 8 + 2 * j] = cacc2[j].x;
    tPart[ty][tx * 8 + 2 * j + 1] = cacc2[j].y;
  }
  __syncthreads();
  if (dual && tid < TILE) {
    float s = 0.0f;
#pragma unroll
    for (int t = 0; t < 16; t++) s += tPart[t][tid];
    part[(pbc * NT + ti) * NPTS + tj * TILE + tid] = s;
  }
}

// ---------------------------------------------------------------------------
// Kernel C1 (grid=64 x 256): final combine (w=0 -> f = ft) for pb=bid>>3,
// chunk=bid&7 (512 points); signed double partial -> RED[bid].
// ---------------------------------------------------------------------------
__global__ __launch_bounds__(256) void k_psum(float* __restrict__ ws)
{
  const int pb = blockIdx.x >> 3, chunk = blockIdx.x & 7;
  const int tid = threadIdx.x;
  const int lpar = (K_TOTAL - 1) & 1;
  const float eps_l = ws[SCHED_OFF + 2 * (K_TOTAL - 1)];

  __shared__ float sfl[32];
  __shared__ float mmS;
  if (tid < 32) {
    const int spb = (pb < 4) ? (pb ^ 2) : pb;
    float ml = ws[ML_OFF + lpar * 256 + spb * NT + tid];
    float mm = ml;
    mm = fmaxf(mm, __shfl_xor(mm, 1, 64));
    mm = fmaxf(mm, __shfl_xor(mm, 2, 64));
    mm = fmaxf(mm, __shfl_xor(mm, 4, 64));
    mm = fmaxf(mm, __shfl_xor(mm, 8, 64));
    mm = fmaxf(mm, __shfl_xor(mm, 16, 64));
    sfl[tid] = EXP2F((ml - mm) * LOG2E);
    if (tid == 0) mmS = mm;
  }
  __syncthreads();

  double acc = 0.0;
#pragma unroll
  for (int rr = 0; rr < 2; rr++) {
    const int r = chunk * 512 + rr * 256 + tid;
    const float* pp = ws + PART_OFF + lpar * PART_SZ + (pb * NT) * NPTS + r;
    float s = 0.0f;
#pragma unroll
    for (int c = 0; c < NT; c++) s += pp[c * NPTS] * sfl[c];
    s = fmaxf(s, 1e-37f);
    float f = -eps_l * fmaf(LN2, LOG2F(s), mmS);
    acc += (double)f;
  }
  for (int o = 32; o; o >>= 1) acc += __shfl_xor(acc, o, 64);
  __shared__ double rd[4];
  if ((tid & 63) == 0) rd[tid >> 6] = acc;
  __syncthreads();
  if (tid == 0) {
    double s = (rd[0] + rd[1]) + (rd[2] + rd[3]);
    ((double*)(ws + RED_OFF))[blockIdx.x] = (pb < 2 * NB) ? s : -s;
  }
}

// ---------------------------------------------------------------------------
// Kernel C2 (1 x 64): deterministic sum of 64 partials -> mean.
// ---------------------------------------------------------------------------
__global__ __launch_bounds__(64) void k_final(const float* __restrict__ ws,
                                              float* __restrict__ out)
{
  double v = ((const double*)(ws + RED_OFF))[threadIdx.x];
  for (int o = 32; o; o >>= 1) v += __shfl_xor(v, o, 64);
  if (threadIdx.x == 0) out[0] = (float)(v / (double)(NB * NPTS));
}

extern "C" void kernel_launch(void* const* d_in, const int* in_sizes, int n_in,
                              void* d_out, int out_size, void* d_ws, size_t ws_size,
                              hipStream_t stream)
{
  const float2* x = (const float2*)d_in[0];  // pre (2,4096,2)
  const float2* y = (const float2*)d_in[1];  // gt  (2,4096,2)
  float* ws = (float*)d_ws;

  k_init<<<64, 256, 0, stream>>>(x, y, ws);

  const int nblocks = NB * NT * NT + 2 * NB * (NT * (NT + 1)) / 2;  // 2048 + 2112
  for (int s = 0; s < K_TOTAL; s++) {
    k_tiles<<<nblocks, BLOCK, 0, stream>>>(x, y, ws, s);
  }
  k_psum<<<64, 256, 0, stream>>>(ws);
  k_final<<<1, 64, 0, stream>>>(ws, (float*)d_out);
}

// Round 17
// 411.602 us; speedup vs baseline: 1.3787x; 1.3787x over previous
//
#include <hip/hip_runtime.h>
#include <math.h>

#define NPTS 4096
#define NB 2
#define K_TOTAL 12
#define BLOCK 256
#define TILE 128
#define NT (NPTS / TILE)   // 32 tile-blocks per dimension

// ws layout (floats / 4B words), double-buffered by step parity:
//  [0..24)     sched: 12 x {eps, w}
//  [32..544)   ML: 2 par x 8 pb x 32 tiles  (tile-local max of h)
//  [576..)     P:  2 par x 8 pb x 4096
//  [66112..)   RED: 64 doubles (block partials of final reduce)
//  [66240..)   PART: 2 par x 8 pb x 32 slots x 4096 (exactly-once writes)
#define SCHED_OFF 0
#define ML_OFF 32
#define P_OFF 576
#define POT_SZ (4 * NB * NPTS)          // 32768
#define RED_OFF (P_OFF + 2 * POT_SZ)    // 66112 (byte offset %8==0: ok for double)
#define PART_OFF (RED_OFF + 128)        // 66240
#define PART_SZ (4 * NB * NT * NPTS)    // 1048576 floats per parity

#if __has_builtin(__builtin_amdgcn_exp2f)
#define EXP2F __builtin_amdgcn_exp2f
#else
#define EXP2F exp2f
#endif
#if __has_builtin(__builtin_amdgcn_logf)
#define LOG2F __builtin_amdgcn_logf
#else
#define LOG2F log2f
#endif
#if __has_builtin(__builtin_amdgcn_sqrtf)
#define FSQRTF __builtin_amdgcn_sqrtf
#else
#define FSQRTF sqrtf
#endif

#define BASE_LOGW -8.31776616671934f  // -log(4096), N==M
#define LOG2E 1.4426950408889634f
#define LN2 0.69314718055994531f

typedef float v2f __attribute__((ext_vector_type(2)));

// ---------------------------------------------------------------------------
// Kernel A (grid=64 x 256): block 0 computes diameter (f32, matching numpy) +
// eps schedule (f64, matching np.arange/np.exp); blocks 1..63 zero both P
// parity buffers.
// ---------------------------------------------------------------------------
__global__ __launch_bounds__(256) void k_init(
    const float2* __restrict__ x, const float2* __restrict__ y, float* ws)
{
  const int tid = threadIdx.x;
  const int bid = blockIdx.x;

  if (bid > 0) {
    for (int i = (bid - 1) * 256 + tid; i < 2 * POT_SZ; i += 63 * 256)
      ws[P_OFF + i] = 0.0f;
    return;
  }

  float mnx = 1e30f, mny = 1e30f, mxx = -1e30f, mxy = -1e30f;
  for (int i = tid; i < NB * NPTS; i += 256) {
    float2 p = x[i];
    mnx = fminf(mnx, p.x); mxx = fmaxf(mxx, p.x);
    mny = fminf(mny, p.y); mxy = fmaxf(mxy, p.y);
    float2 q = y[i];
    mnx = fminf(mnx, q.x); mxx = fmaxf(mxx, q.x);
    mny = fminf(mny, q.y); mxy = fmaxf(mxy, q.y);
  }
  for (int o = 32; o; o >>= 1) {
    mnx = fminf(mnx, __shfl_xor(mnx, o, 64));
    mxx = fmaxf(mxx, __shfl_xor(mxx, o, 64));
    mny = fminf(mny, __shfl_xor(mny, o, 64));
    mxy = fmaxf(mxy, __shfl_xor(mxy, o, 64));
  }
  __shared__ float r[4][4];
  const int wave = tid >> 6, lane = tid & 63;
  if (lane == 0) { r[0][wave] = mnx; r[1][wave] = mxx; r[2][wave] = mny; r[3][wave] = mxy; }
  __syncthreads();
  if (tid == 0) {
    mnx = fminf(fminf(r[0][0], r[0][1]), fminf(r[0][2], r[0][3]));
    mxx = fmaxf(fmaxf(r[1][0], r[1][1]), fmaxf(r[1][2], r[1][3]));
    mny = fminf(fminf(r[2][0], r[2][1]), fminf(r[2][2], r[2][3]));
    mxy = fmaxf(fmaxf(r[3][0], r[3][1]), fmaxf(r[3][2], r[3][3]));
    float rx = mxx - mnx, ry = mxy - mny;
    float dia = sqrtf(rx * rx + ry * ry);

    double a = log((double)dia);
    double stop = log(0.05);
    double stp = log(0.5);
    int cnt = (int)ceil((stop - a) / stp);  // data: cnt == 8
    if (cnt < 0) cnt = 0;
    if (cnt > K_TOTAL - 4) cnt = K_TOTAL - 4;

    float* sch = ws + SCHED_OFF;
    sch[0] = dia; sch[1] = 0.0f;   // init: direct assign at eps=diameter
    sch[2] = dia; sch[3] = 0.5f;   // loop over eps_list, w=0.5
    for (int k = 0; k < cnt; k++) {
      sch[2 * (2 + k)] = (float)exp(a + (double)k * stp);
      sch[2 * (2 + k) + 1] = 0.5f;
    }
    sch[2 * (2 + cnt)] = 0.05f; sch[2 * (2 + cnt) + 1] = 0.5f;
    for (int s = 3 + cnt; s < K_TOTAL - 1; s++) { sch[2 * s] = 0.05f; sch[2 * s + 1] = 1.0f; }
    sch[2 * (K_TOTAL - 1)] = 0.05f; sch[2 * (K_TOTAL - 1) + 1] = 0.0f;  // final extrapolation
  }
}

// ---------------------------------------------------------------------------
// Kernel B: 256-thread K-tile sweep with fused combine -- the session's
// measured optimum (412.5 / 412.6 / 413.0 us across three runs).
// Staging of step t performs step t-1's combine for this block's 256 points:
//   S_i = sum_c part_prev[pb][c][i] * exp(ML_prev[spb][c] - Mmax)
//   ft  = -eps_prev * (ln2*log2(S) + Mmax);  P_new = mix(w_prev, P_old, ft)
// then h = logw + P_new/eps_t, V = exp(h - Mloc(own tile)); Mloc -> ML[cur]
// (benign identical-value race). Parity double-buffering:
//   reads P[stepi&1], parts/ML[(stepi-1)&1]; writes P[(stepi-1)&1],
//   parts/ML[stepi&1].
// Inner loop: packed f32 (v_pk ops), 8 rows x 8 cols per thread.
// blocks: [0,2048) cross; [2048,4160) self via closed-form triangle index.
// launch_bounds (256,4) is the max spill-free occupancy: natural VGPR is in
// (85,128] -- (256,6)/(256,8) spill to scratch (r16/r4), (256,2) is null
// (r10). Also falsified: 512-thread split (+6us, r8), cross-tile pairing
// (liveness-range spill, r11-r14), global atomics (+18us, r5).
// ---------------------------------------------------------------------------
__global__ __launch_bounds__(BLOCK, 4) void k_tiles(
    const float2* __restrict__ xpts, const float2* __restrict__ ypts,
    float* __restrict__ ws, int stepi)
{
  __shared__ float rXs[TILE], rYs[TILE], rVs[TILE];
  __shared__ float cXs[144], cYs[144], cVs[144];  // padded: idx + idx/8
  __shared__ float tPart[16][129];                // reused for rows then cols
  __shared__ float sfb[2][32];                    // combine scale factors per side
  __shared__ float smx[2];                        // Mmax per side
  __shared__ float wmax[4];                       // per-wave h-max scratch

  const int tid = threadIdx.x;
  const int id = blockIdx.x;

  const float2* rowp; const float2* colp;
  int ti, tj, pbr, pbc;
  bool dual;

  if (id < NB * NT * NT) {
    const int b = id >> 10;
    const int t = id & (NT * NT - 1);
    ti = t >> 5; tj = t & (NT - 1);
    rowp = xpts + b * NPTS; colp = ypts + b * NPTS;
    pbr = 0 * NB + b; pbc = 1 * NB + b;   // rows: f_ba side; cols: g_ab side
    dual = true;
  } else {
    const int id2 = id - NB * NT * NT;    // [0, 2112)
    const int mat = id2 / 1056;           // 0: C_xx, 1: C_yy
    const int rem = id2 - mat * 1056;
    const int b = rem / 528;
    const int k = rem - b * 528;          // triangle index, ti <= tj
    int t0 = (int)((65.0f - FSQRTF((float)(4225 - 8 * k))) * 0.5f);
    while (t0 * (65 - t0) / 2 > k) t0--;
    while ((t0 + 1) * (64 - t0) / 2 <= k) t0++;
    ti = t0; tj = t0 + (k - t0 * (65 - t0) / 2);
    const float2* pts = mat ? ypts : xpts;
    rowp = pts + b * NPTS; colp = rowp;
    pbr = (2 + mat) * NB + b; pbc = pbr;
    dual = (ti != tj);                    // diagonal tile: row sums only
  }

  const float eps = ws[SCHED_OFF + 2 * stepi];
  const float sc = LOG2E / eps;       // exp2(-sqrt(d2_scaled)) = e^{-d/eps}
  const float inv_eps = 1.0f / eps;   // h = logw + P/eps
  const int ppar = (stepi - 1) & 1;   // parity of prev step's parts/ML; P_new written here
  const int cpar = stepi & 1;         // parity of this step's parts/ML; P_old read here

  // ---- Phase A: wave 0 builds combine scale factors from prev-step ML ----
  if (stepi > 0 && tid < 64) {
    const int c = tid & 31, side = tid >> 5;
    const int pb_own = side ? pbc : pbr;
    const int spb = (pb_own < 4) ? (pb_own ^ 2) : pb_own;  // V-pot partner
    float ml = ws[ML_OFF + ppar * 256 + spb * NT + c];
    float mm = ml;
    mm = fmaxf(mm, __shfl_xor(mm, 1, 64));
    mm = fmaxf(mm, __shfl_xor(mm, 2, 64));
    mm = fmaxf(mm, __shfl_xor(mm, 4, 64));
    mm = fmaxf(mm, __shfl_xor(mm, 8, 64));
    mm = fmaxf(mm, __shfl_xor(mm, 16, 64));
    sfb[side][c] = EXP2F((ml - mm) * LOG2E);
    if (c == 0) smx[side] = mm;
  }
  __syncthreads();

  // ---- Phase B: per-point combine (step t-1) + h ----
  const int side = tid >> 7, kk0 = tid & 127;
  const int pb_own = side ? pbc : pbr;
  const int tile_own = side ? tj : ti;
  const int r = tile_own * TILE + kk0;
  float2 pt = (side ? colp : rowp)[r];

  float h;
  if (stepi == 0) {
    h = BASE_LOGW;                     // P = 0
  } else {
    const float eps_p = ws[SCHED_OFF + 2 * (stepi - 1)];
    const float w_p = ws[SCHED_OFF + 2 * (stepi - 1) + 1];
    const float* pprev = ws + PART_OFF + ppar * PART_SZ + (pb_own * NT) * NPTS + r;
    float s = 0.0f;
#pragma unroll
    for (int c = 0; c < NT; c++) s += pprev[c * NPTS] * sfb[side][c];
    s = fmaxf(s, 1e-37f);
    float ft = -eps_p * fmaf(LN2, LOG2F(s), smx[side]);
    float po = ws[P_OFF + cpar * POT_SZ + pb_own * NPTS + r];
    float pn = (w_p >= 1.0f) ? po : fmaf(w_p, po, (1.0f - w_p) * ft);
    ws[P_OFF + ppar * POT_SZ + pb_own * NPTS + r] = pn;  // identical-value race OK
    h = fmaf(pn, inv_eps, BASE_LOGW);
  }

  // ---- per-side Mloc = max h over the side's 128 points ----
  float hm = h;
  for (int o = 32; o; o >>= 1) hm = fmaxf(hm, __shfl_xor(hm, o, 64));
  if ((tid & 63) == 0) wmax[tid >> 6] = hm;
  __syncthreads();
  const float Mloc = fmaxf(wmax[2 * side], wmax[2 * side + 1]);

  // ---- Phase C: stage scaled coords + V; record ML ----
  if (side == 0) {
    rXs[kk0] = pt.x * sc; rYs[kk0] = pt.y * sc;
    rVs[kk0] = EXP2F((h - Mloc) * LOG2E);
  } else {
    const int kk = kk0 + (kk0 >> 3);  // pad to break 4-way preload conflict
    cXs[kk] = pt.x * sc; cYs[kk] = pt.y * sc;
    cVs[kk] = EXP2F((h - Mloc) * LOG2E);
  }
  if (kk0 == 0) ws[ML_OFF + cpar * 256 + pb_own * NT + tile_own] = Mloc;
  __syncthreads();

  // ---- inner loop: packed f32, 8 rows x 8 cols per thread ----
  const int tx = tid & 15, ty = tid >> 4;
  float rx[8], ry[8], rv[8];
  v2f cx2[4], cy2[4], cv2[4], racc2[8], cacc2[4];
#pragma unroll
  for (int q = 0; q < 8; q++) {
    rx[q] = rXs[ty * 8 + q]; ry[q] = rYs[ty * 8 + q]; rv[q] = rVs[ty * 8 + q];
    racc2[q] = (v2f){0.0f, 0.0f};
  }
#pragma unroll
  for (int j = 0; j < 4; j++) {
    const int ci = tx * 9 + 2 * j;
    cx2[j] = (v2f){cXs[ci], cXs[ci + 1]};
    cy2[j] = (v2f){cYs[ci], cYs[ci + 1]};
    cv2[j] = (v2f){cVs[ci], cVs[ci + 1]};
    cacc2[j] = (v2f){0.0f, 0.0f};
  }

#pragma unroll
  for (int q = 0; q < 8; q++) {
    const v2f rxq = (v2f){rx[q], rx[q]};
    const v2f ryq = (v2f){ry[q], ry[q]};
    const v2f rvq = (v2f){rv[q], rv[q]};
#pragma unroll
    for (int j = 0; j < 4; j++) {
      v2f dx = rxq - cx2[j];
      v2f dy = ryq - cy2[j];
      v2f d2 = dx * dx + dy * dy;
      float t0 = FSQRTF(d2.x), t1 = FSQRTF(d2.y);
      v2f K = (v2f){EXP2F(-t0), EXP2F(-t1)};
      racc2[q] += K * cv2[j];
      cacc2[j] += K * rvq;
    }
  }

  float* part = ws + PART_OFF + cpar * PART_SZ;

  // rows: transpose via LDS, 128-lane sum, store to slot tj
#pragma unroll
  for (int q = 0; q < 8; q++) tPart[tx][ty * 8 + q] = racc2[q].x + racc2[q].y;
  __syncthreads();
  if (tid < TILE) {
    float s = 0.0f;
#pragma unroll
    for (int t = 0; t < 16; t++) s += tPart[t][tid];
    part[(pbr * NT + tj) * NPTS + ti * TILE + tid] = s;
  }
  __syncthreads();

  // cols: same buffer, slot ti
#pragma unroll
  for (int j = 0; j < 4; j++) {
    tPart[ty][tx * 8 + 2 * j] = cacc2[j].x;
    tPart[ty][tx * 8 + 2 * j + 1] = cacc2[j].y;
  }
  __syncthreads();
  if (dual && tid < TILE) {
    float s = 0.0f;
#pragma unroll
    for (int t = 0; t < 16; t++) s += tPart[t][tid];
    part[(pbc * NT + ti) * NPTS + tj * TILE + tid] = s;
  }
}

// ---------------------------------------------------------------------------
// Kernel C1 (grid=64 x 256): final combine (w=0 -> f = ft) for pb=bid>>3,
// chunk=bid&7 (512 points); signed double partial -> RED[bid].
// ---------------------------------------------------------------------------
__global__ __launch_bounds__(256) void k_psum(float* __restrict__ ws)
{
  const int pb = blockIdx.x >> 3, chunk = blockIdx.x & 7;
  const int tid = threadIdx.x;
  const int lpar = (K_TOTAL - 1) & 1;
  const float eps_l = ws[SCHED_OFF + 2 * (K_TOTAL - 1)];

  __shared__ float sfl[32];
  __shared__ float mmS;
  if (tid < 32) {
    const int spb = (pb < 4) ? (pb ^ 2) : pb;
    float ml = ws[ML_OFF + lpar * 256 + spb * NT + tid];
    float mm = ml;
    mm = fmaxf(mm, __shfl_xor(mm, 1, 64));
    mm = fmaxf(mm, __shfl_xor(mm, 2, 64));
    mm = fmaxf(mm, __shfl_xor(mm, 4, 64));
    mm = fmaxf(mm, __shfl_xor(mm, 8, 64));
    mm = fmaxf(mm, __shfl_xor(mm, 16, 64));
    sfl[tid] = EXP2F((ml - mm) * LOG2E);
    if (tid == 0) mmS = mm;
  }
  __syncthreads();

  double acc = 0.0;
#pragma unroll
  for (int rr = 0; rr < 2; rr++) {
    const int r = chunk * 512 + rr * 256 + tid;
    const float* pp = ws + PART_OFF + lpar * PART_SZ + (pb * NT) * NPTS + r;
    float s = 0.0f;
#pragma unroll
    for (int c = 0; c < NT; c++) s += pp[c * NPTS] * sfl[c];
    s = fmaxf(s, 1e-37f);
    float f = -eps_l * fmaf(LN2, LOG2F(s), mmS);
    acc += (double)f;
  }
  for (int o = 32; o; o >>= 1) acc += __shfl_xor(acc, o, 64);
  __shared__ double rd[4];
  if ((tid & 63) == 0) rd[tid >> 6] = acc;
  __syncthreads();
  if (tid == 0) {
    double s = (rd[0] + rd[1]) + (rd[2] + rd[3]);
    ((double*)(ws + RED_OFF))[blockIdx.x] = (pb < 2 * NB) ? s : -s;
  }
}

// ---------------------------------------------------------------------------
// Kernel C2 (1 x 64): deterministic sum of 64 partials -> mean.
// ---------------------------------------------------------------------------
__global__ __launch_bounds__(64) void k_final(const float* __restrict__ ws,
                                              float* __restrict__ out)
{
  double v = ((const double*)(ws + RED_OFF))[threadIdx.x];
  for (int o = 32; o; o >>= 1) v += __shfl_xor(v, o, 64);
  if (threadIdx.x == 0) out[0] = (float)(v / (double)(NB * NPTS));
}

extern "C" void kernel_launch(void* const* d_in, const int* in_sizes, int n_in,
                              void* d_out, int out_size, void* d_ws, size_t ws_size,
                              hipStream_t stream)
{
  const float2* x = (const float2*)d_in[0];  // pre (2,4096,2)
  const float2* y = (const float2*)d_in[1];  // gt  (2,4096,2)
  float* ws = (float*)d_ws;

  k_init<<<64, 256, 0, stream>>>(x, y, ws);

  const int nblocks = NB * NT * NT + 2 * NB * (NT * (NT + 1)) / 2;  // 2048 + 2112
  for (int s = 0; s < K_TOTAL; s++) {
    k_tiles<<<nblocks, BLOCK, 0, stream>>>(x, y, ws, s);
  }
  k_psum<<<64, 256, 0, stream>>>(ws);
  k_final<<<1, 64, 0, stream>>>(ws, (float*)d_out);
}